// Round 1
// baseline (528.953 us; speedup 1.0000x reference)
//
#include <hip/hip_runtime.h>
#include <math.h>

#define NBATCH 64
#define Q      1000
#define C      1203
#define QC     1203000      // Q*C
#define QC4    300750       // QC/4
#define K      100
#define NBINS  2048         // top 11 bits of monotonic key
#define CAP    1024         // candidate capacity per batch
#define BPB    32           // blocks per batch for the two big passes
#define BS     256

// monotonic uint key: key increasing <=> float increasing
__device__ __forceinline__ unsigned int mono_key(float x) {
    unsigned int u = __float_as_uint(x);
    return u ^ ((u >> 31) ? 0xFFFFFFFFu : 0x80000000u);
}
__device__ __forceinline__ float key_to_float(unsigned int k) {
    unsigned int u = (k & 0x80000000u) ? (k ^ 0x80000000u) : ~k;
    return __uint_as_float(u);
}

__global__ void __launch_bounds__(BS) zero_kernel(unsigned int* hist, unsigned int* cnt) {
    int i = blockIdx.x * BS + threadIdx.x;
    if (i < NBATCH * NBINS) hist[i] = 0u;
    if (i < NBATCH) cnt[i] = 0u;
}

__global__ void __launch_bounds__(BS) hist_kernel(const float* __restrict__ logits,
                                                  unsigned int* __restrict__ hist) {
    __shared__ unsigned int lh[NBINS];
    int b   = blockIdx.x / BPB;
    int sub = blockIdx.x % BPB;
    for (int i = threadIdx.x; i < NBINS; i += BS) lh[i] = 0u;
    __syncthreads();
    const float4* src = (const float4*)(logits + (size_t)b * QC);
    for (int i = sub * BS + threadIdx.x; i < QC4; i += BPB * BS) {
        float4 v = src[i];
        atomicAdd(&lh[mono_key(v.x) >> 21], 1u);
        atomicAdd(&lh[mono_key(v.y) >> 21], 1u);
        atomicAdd(&lh[mono_key(v.z) >> 21], 1u);
        atomicAdd(&lh[mono_key(v.w) >> 21], 1u);
    }
    __syncthreads();
    unsigned int* gh = hist + (size_t)b * NBINS;
    for (int i = threadIdx.x; i < NBINS; i += BS) {
        unsigned int c = lh[i];
        if (c) atomicAdd(&gh[i], c);
    }
}

// one block per batch: find bin tb s.t. suffix count >= K; thresh = tb<<21
__global__ void __launch_bounds__(BS) select_kernel(const unsigned int* __restrict__ hist,
                                                    unsigned int* __restrict__ thresh) {
    __shared__ unsigned int lh[NBINS];
    __shared__ unsigned int seg[BS];
    int b = blockIdx.x;
    const unsigned int* gh = hist + (size_t)b * NBINS;
    unsigned int s = 0;
    for (int j = 0; j < NBINS / BS; ++j) {
        unsigned int v = gh[threadIdx.x + j * BS];
        lh[threadIdx.x + j * BS] = v;
        s += v;
    }
    // seg[t] = sum of bins [t*8, t*8+8)  -- NOT contiguous with loads above; recompute
    __syncthreads();
    unsigned int segsum = 0;
    for (int j = 0; j < NBINS / BS; ++j) segsum += lh[threadIdx.x * (NBINS / BS) + j];
    seg[threadIdx.x] = segsum;
    __syncthreads();
    if (threadIdx.x == 0) {
        unsigned int cum = 0;
        int tb = 0;
        for (int sgi = BS - 1; sgi >= 0; --sgi) {
            if (cum + seg[sgi] >= K) {
                // walk bins inside this segment from the top
                int hi = sgi * (NBINS / BS) + (NBINS / BS) - 1;
                int lo = sgi * (NBINS / BS);
                for (int i = hi; i >= lo; --i) {
                    cum += lh[i];
                    if (cum >= K) { tb = i; break; }
                }
                break;
            }
            cum += seg[sgi];
        }
        thresh[b] = ((unsigned int)tb) << 21;
    }
}

__global__ void __launch_bounds__(BS) collect_kernel(const float* __restrict__ logits,
                                                     const unsigned int* __restrict__ thresh,
                                                     unsigned int* __restrict__ cnt,
                                                     uint2* __restrict__ cand) {
    int b   = blockIdx.x / BPB;
    int sub = blockIdx.x % BPB;
    unsigned int tk = thresh[b];
    const float4* src = (const float4*)(logits + (size_t)b * QC);
    uint2* cb = cand + (size_t)b * CAP;
    for (int i = sub * BS + threadIdx.x; i < QC4; i += BPB * BS) {
        float4 v = src[i];
        unsigned int base = 4u * (unsigned int)i;
        unsigned int k0 = mono_key(v.x);
        unsigned int k1 = mono_key(v.y);
        unsigned int k2 = mono_key(v.z);
        unsigned int k3 = mono_key(v.w);
        if (k0 >= tk) { unsigned int s = atomicAdd(&cnt[b], 1u); if (s < CAP) cb[s] = make_uint2(k0, base + 0u); }
        if (k1 >= tk) { unsigned int s = atomicAdd(&cnt[b], 1u); if (s < CAP) cb[s] = make_uint2(k1, base + 1u); }
        if (k2 >= tk) { unsigned int s = atomicAdd(&cnt[b], 1u); if (s < CAP) cb[s] = make_uint2(k2, base + 2u); }
        if (k3 >= tk) { unsigned int s = atomicAdd(&cnt[b], 1u); if (s < CAP) cb[s] = make_uint2(k3, base + 3u); }
    }
}

__global__ void __launch_bounds__(BS) output_kernel(const unsigned int* __restrict__ cnt,
                                                    const uint2* __restrict__ cand,
                                                    const float* __restrict__ bbox,
                                                    const float* __restrict__ tsizes,
                                                    float* __restrict__ out) {
    __shared__ uint2 sc[CAP];
    int b = blockIdx.x;
    unsigned int n = cnt[b];
    if (n > CAP) n = CAP;
    const uint2* cb = cand + (size_t)b * CAP;
    for (unsigned int i = threadIdx.x; i < n; i += BS) sc[i] = cb[i];
    __syncthreads();
    float img_h = tsizes[2 * b + 0];
    float img_w = tsizes[2 * b + 1];
    float* scores = out;
    float* labels = out + NBATCH * K;
    float* boxes  = out + 2 * NBATCH * K;
    for (unsigned int i = threadIdx.x; i < n; i += BS) {
        uint2 me = sc[i];
        int rank = 0;
        for (unsigned int j = 0; j < n; ++j) {
            uint2 o = sc[j];
            if (o.x > me.x || (o.x == me.x && o.y < me.y)) rank++;
        }
        if (rank < K) {
            float v = key_to_float(me.x);
            double sd = 1.0 / (1.0 + exp(-(double)v));
            scores[b * K + rank] = (float)sd;
            unsigned int idx = me.y;
            unsigned int q   = idx / C;
            unsigned int lab = idx - q * C;
            labels[b * K + rank] = (float)lab;
            const float* bb = bbox + ((size_t)b * Q + q) * 4;
            float cx = bb[0], cy = bb[1], w = bb[2], h = bb[3];
            float x0 = cx - 0.5f * w;
            float y0 = cy - 0.5f * h;
            float x1 = cx + 0.5f * w;
            float y1 = cy + 0.5f * h;
            float* o = boxes + ((size_t)b * K + (size_t)rank) * 4;
            o[0] = x0 * img_w;
            o[1] = y0 * img_h;
            o[2] = x1 * img_w;
            o[3] = y1 * img_h;
        }
    }
}

extern "C" void kernel_launch(void* const* d_in, const int* in_sizes, int n_in,
                              void* d_out, int out_size, void* d_ws, size_t ws_size,
                              hipStream_t stream) {
    const float* logits = (const float*)d_in[0];   // 64*1000*1203
    const float* bbox   = (const float*)d_in[1];   // 64*1000*4
    const float* tsizes = (const float*)d_in[2];   // 64*2
    float* out = (float*)d_out;

    char* ws = (char*)d_ws;
    unsigned int* hist   = (unsigned int*)(ws);                       // 64*2048*4 = 524288
    unsigned int* cnt    = (unsigned int*)(ws + 524288);              // 256
    unsigned int* thresh = (unsigned int*)(ws + 524544);              // 256
    uint2*        cand   = (uint2*)(ws + 524800);                     // 64*1024*8 = 524288

    int zgrid = (NBATCH * NBINS + BS - 1) / BS;
    zero_kernel<<<zgrid, BS, 0, stream>>>(hist, cnt);
    hist_kernel<<<NBATCH * BPB, BS, 0, stream>>>(logits, hist);
    select_kernel<<<NBATCH, BS, 0, stream>>>(hist, thresh);
    collect_kernel<<<NBATCH * BPB, BS, 0, stream>>>(logits, thresh, cnt, cand);
    output_kernel<<<NBATCH, BS, 0, stream>>>(cnt, cand, bbox, tsizes, out);
}

// Round 2
// 463.347 us; speedup vs baseline: 1.1416x; 1.1416x over previous
//
#include <hip/hip_runtime.h>
#include <math.h>

#define NBATCH 64
#define Q      1000
#define C      1203
#define QC     1203000      // Q*C
#define QC4    300750       // QC/4
#define K      100
#define NBINS  2048         // top 11 bits of monotonic key (fallback path)
#define CAP    1024         // candidate capacity per batch
#define BPB    32           // blocks per batch for the big passes
#define BS     256
#define TLOGIT 3.4f         // fast-path collect threshold (exp ~405/batch for N(0,1))

// monotonic uint key: key increasing <=> float increasing
__device__ __forceinline__ unsigned int mono_key(float x) {
    unsigned int u = __float_as_uint(x);
    return u ^ ((u >> 31) ? 0xFFFFFFFFu : 0x80000000u);
}
__device__ __forceinline__ float key_to_float(unsigned int k) {
    unsigned int u = (k & 0x80000000u) ? (k ^ 0x80000000u) : ~k;
    return __uint_as_float(u);
}

__global__ void __launch_bounds__(BS) zero_kernel(unsigned int* hist, unsigned int* cnt,
                                                  unsigned int* flags) {
    int i = blockIdx.x * BS + threadIdx.x;
    if (i < NBATCH * NBINS) hist[i] = 0u;
    if (i < NBATCH) { cnt[i] = 0u; flags[i] = 0u; }
}

// Fast path: single full read; collect candidates >= fixed logit threshold.
__global__ void __launch_bounds__(BS) pass1_kernel(const float* __restrict__ logits,
                                                   unsigned int* __restrict__ cnt,
                                                   uint2* __restrict__ cand) {
    int b   = blockIdx.x / BPB;
    int sub = blockIdx.x % BPB;
    const float4* src = (const float4*)(logits + (size_t)b * QC);
    uint2* cb = cand + (size_t)b * CAP;
    for (int i = sub * BS + threadIdx.x; i < QC4; i += BPB * BS) {
        float4 v = src[i];
        unsigned int base = 4u * (unsigned int)i;
        if (v.x >= TLOGIT) { unsigned int s = atomicAdd(&cnt[b], 1u); if (s < CAP) cb[s] = make_uint2(mono_key(v.x), base + 0u); }
        if (v.y >= TLOGIT) { unsigned int s = atomicAdd(&cnt[b], 1u); if (s < CAP) cb[s] = make_uint2(mono_key(v.y), base + 1u); }
        if (v.z >= TLOGIT) { unsigned int s = atomicAdd(&cnt[b], 1u); if (s < CAP) cb[s] = make_uint2(mono_key(v.z), base + 2u); }
        if (v.w >= TLOGIT) { unsigned int s = atomicAdd(&cnt[b], 1u); if (s < CAP) cb[s] = make_uint2(mono_key(v.w), base + 3u); }
    }
}

// Check fast path validity per batch; arm fallback where it failed.
__global__ void flag_kernel(unsigned int* __restrict__ cnt,
                            unsigned int* __restrict__ flags) {
    int b = threadIdx.x;
    if (b < NBATCH) {
        unsigned int n = cnt[b];
        unsigned int f = (n < (unsigned int)K || n > (unsigned int)CAP) ? 1u : 0u;
        flags[b] = f;
        if (f) cnt[b] = 0u;   // fallback collect restarts this batch
    }
}

// ---- Fallback path (exact histogram select); early-exits unless flagged ----
__global__ void __launch_bounds__(BS) hist_kernel(const float* __restrict__ logits,
                                                  const unsigned int* __restrict__ flags,
                                                  unsigned int* __restrict__ hist) {
    int b = blockIdx.x / BPB;
    if (!flags[b]) return;
    __shared__ unsigned int lh[NBINS];
    int sub = blockIdx.x % BPB;
    for (int i = threadIdx.x; i < NBINS; i += BS) lh[i] = 0u;
    __syncthreads();
    const float4* src = (const float4*)(logits + (size_t)b * QC);
    for (int i = sub * BS + threadIdx.x; i < QC4; i += BPB * BS) {
        float4 v = src[i];
        atomicAdd(&lh[mono_key(v.x) >> 21], 1u);
        atomicAdd(&lh[mono_key(v.y) >> 21], 1u);
        atomicAdd(&lh[mono_key(v.z) >> 21], 1u);
        atomicAdd(&lh[mono_key(v.w) >> 21], 1u);
    }
    __syncthreads();
    unsigned int* gh = hist + (size_t)b * NBINS;
    for (int i = threadIdx.x; i < NBINS; i += BS) {
        unsigned int c = lh[i];
        if (c) atomicAdd(&gh[i], c);
    }
}

__global__ void __launch_bounds__(BS) select_kernel(const unsigned int* __restrict__ hist,
                                                    const unsigned int* __restrict__ flags,
                                                    unsigned int* __restrict__ thresh) {
    int b = blockIdx.x;
    if (!flags[b]) return;
    __shared__ unsigned int lh[NBINS];
    __shared__ unsigned int seg[BS];
    const unsigned int* gh = hist + (size_t)b * NBINS;
    for (int j = 0; j < NBINS / BS; ++j)
        lh[threadIdx.x + j * BS] = gh[threadIdx.x + j * BS];
    __syncthreads();
    unsigned int segsum = 0;
    for (int j = 0; j < NBINS / BS; ++j) segsum += lh[threadIdx.x * (NBINS / BS) + j];
    seg[threadIdx.x] = segsum;
    __syncthreads();
    if (threadIdx.x == 0) {
        unsigned int cum = 0;
        int tb = 0;
        for (int sgi = BS - 1; sgi >= 0; --sgi) {
            if (cum + seg[sgi] >= K) {
                int hi = sgi * (NBINS / BS) + (NBINS / BS) - 1;
                int lo = sgi * (NBINS / BS);
                for (int i = hi; i >= lo; --i) {
                    cum += lh[i];
                    if (cum >= K) { tb = i; break; }
                }
                break;
            }
            cum += seg[sgi];
        }
        thresh[b] = ((unsigned int)tb) << 21;
    }
}

__global__ void __launch_bounds__(BS) collect_kernel(const float* __restrict__ logits,
                                                     const unsigned int* __restrict__ flags,
                                                     const unsigned int* __restrict__ thresh,
                                                     unsigned int* __restrict__ cnt,
                                                     uint2* __restrict__ cand) {
    int b = blockIdx.x / BPB;
    if (!flags[b]) return;
    int sub = blockIdx.x % BPB;
    unsigned int tk = thresh[b];
    const float4* src = (const float4*)(logits + (size_t)b * QC);
    uint2* cb = cand + (size_t)b * CAP;
    for (int i = sub * BS + threadIdx.x; i < QC4; i += BPB * BS) {
        float4 v = src[i];
        unsigned int base = 4u * (unsigned int)i;
        unsigned int k0 = mono_key(v.x);
        unsigned int k1 = mono_key(v.y);
        unsigned int k2 = mono_key(v.z);
        unsigned int k3 = mono_key(v.w);
        if (k0 >= tk) { unsigned int s = atomicAdd(&cnt[b], 1u); if (s < CAP) cb[s] = make_uint2(k0, base + 0u); }
        if (k1 >= tk) { unsigned int s = atomicAdd(&cnt[b], 1u); if (s < CAP) cb[s] = make_uint2(k1, base + 1u); }
        if (k2 >= tk) { unsigned int s = atomicAdd(&cnt[b], 1u); if (s < CAP) cb[s] = make_uint2(k2, base + 2u); }
        if (k3 >= tk) { unsigned int s = atomicAdd(&cnt[b], 1u); if (s < CAP) cb[s] = make_uint2(k3, base + 3u); }
    }
}

// Exact top-K among candidates: rank by (key desc, idx asc); write outputs.
__global__ void __launch_bounds__(BS) output_kernel(const unsigned int* __restrict__ cnt,
                                                    const uint2* __restrict__ cand,
                                                    const float* __restrict__ bbox,
                                                    const float* __restrict__ tsizes,
                                                    float* __restrict__ out) {
    __shared__ uint2 sc[CAP];
    int b = blockIdx.x;
    unsigned int n = cnt[b];
    if (n > CAP) n = CAP;
    const uint2* cb = cand + (size_t)b * CAP;
    for (unsigned int i = threadIdx.x; i < n; i += BS) sc[i] = cb[i];
    __syncthreads();
    float img_h = tsizes[2 * b + 0];
    float img_w = tsizes[2 * b + 1];
    float* scores = out;
    float* labels = out + NBATCH * K;
    float* boxes  = out + 2 * NBATCH * K;
    for (unsigned int i = threadIdx.x; i < n; i += BS) {
        uint2 me = sc[i];
        int rank = 0;
        for (unsigned int j = 0; j < n; ++j) {
            uint2 o = sc[j];
            if (o.x > me.x || (o.x == me.x && o.y < me.y)) rank++;
        }
        if (rank < K) {
            float v = key_to_float(me.x);
            double sd = 1.0 / (1.0 + exp(-(double)v));
            scores[b * K + rank] = (float)sd;
            unsigned int idx = me.y;
            unsigned int q   = idx / C;
            unsigned int lab = idx - q * C;
            labels[b * K + rank] = (float)lab;
            const float* bb = bbox + ((size_t)b * Q + q) * 4;
            float cx = bb[0], cy = bb[1], w = bb[2], h = bb[3];
            float* o = boxes + ((size_t)b * K + (size_t)rank) * 4;
            o[0] = (cx - 0.5f * w) * img_w;
            o[1] = (cy - 0.5f * h) * img_h;
            o[2] = (cx + 0.5f * w) * img_w;
            o[3] = (cy + 0.5f * h) * img_h;
        }
    }
}

extern "C" void kernel_launch(void* const* d_in, const int* in_sizes, int n_in,
                              void* d_out, int out_size, void* d_ws, size_t ws_size,
                              hipStream_t stream) {
    const float* logits = (const float*)d_in[0];   // 64*1000*1203
    const float* bbox   = (const float*)d_in[1];   // 64*1000*4
    const float* tsizes = (const float*)d_in[2];   // 64*2
    float* out = (float*)d_out;

    char* ws = (char*)d_ws;
    unsigned int* hist   = (unsigned int*)(ws);                       // 512 KiB
    unsigned int* cnt    = (unsigned int*)(ws + 524288);              // 256 B
    unsigned int* thresh = (unsigned int*)(ws + 524544);              // 256 B
    unsigned int* flags  = (unsigned int*)(ws + 524800);              // 256 B
    uint2*        cand   = (uint2*)(ws + 525056);                     // 512 KiB

    int zgrid = (NBATCH * NBINS + BS - 1) / BS;
    zero_kernel<<<zgrid, BS, 0, stream>>>(hist, cnt, flags);
    pass1_kernel<<<NBATCH * BPB, BS, 0, stream>>>(logits, cnt, cand);
    flag_kernel<<<1, 64, 0, stream>>>(cnt, flags);
    hist_kernel<<<NBATCH * BPB, BS, 0, stream>>>(logits, flags, hist);
    select_kernel<<<NBATCH, BS, 0, stream>>>(hist, flags, thresh);
    collect_kernel<<<NBATCH * BPB, BS, 0, stream>>>(logits, flags, thresh, cnt, cand);
    output_kernel<<<NBATCH, BS, 0, stream>>>(cnt, cand, bbox, tsizes, out);
}